// Round 1
// baseline (154.403 us; speedup 1.0000x reference)
//
#include <hip/hip_runtime.h>
#include <math.h>

#define NN 8192
#define SSEG 32
#define JCH (NN / SSEG)

// ---------------- workspace layout (in floats) ----------------
constexpr size_t OFF_XN   = 0;                                 // [NN][8] normalized rows
constexpr size_t OFF_PNS  = OFF_XN + (size_t)NN * 8;           // [SSEG][NN][8] partial neighbour sums
constexpr size_t OFF_DIF  = OFF_PNS + (size_t)SSEG * NN * 8;   // [NN][8] diffused
constexpr size_t OFF_QS   = OFF_DIF + (size_t)NN * 8;          // [NN][8] q pre-scaled by log2e/sqrt(8)
constexpr size_t OFF_KK   = OFF_QS + (size_t)NN * 8;           // [NN][8] k
constexpr size_t OFF_PACC = OFF_KK + (size_t)NN * 8;           // [SSEG][NN][8] partial attn accum
constexpr size_t OFF_PM   = OFF_PACC + (size_t)SSEG * NN * 8;  // [SSEG][NN] partial max
constexpr size_t OFF_PSUM = OFF_PM + (size_t)SSEG * NN;        // [SSEG][NN] partial sum

// ---------------- kernel 1: row normalize ----------------
__global__ __launch_bounds__(256) void k_norm(const float* __restrict__ in,
                                              float* __restrict__ xn) {
    int r = blockIdx.x * 256 + threadIdx.x;
    const float4* p = reinterpret_cast<const float4*>(in + r * 8);
    float4 a = p[0], b = p[1];
    float ss = a.x*a.x + a.y*a.y + a.z*a.z + a.w*a.w
             + b.x*b.x + b.y*b.y + b.z*b.z + b.w*b.w;
    float inv = 1.0f / (sqrtf(ss) + 1e-12f);
    a.x *= inv; a.y *= inv; a.z *= inv; a.w *= inv;
    b.x *= inv; b.y *= inv; b.z *= inv; b.w *= inv;
    float4* o = reinterpret_cast<float4*>(xn + r * 8);
    o[0] = a; o[1] = b;
}

// ---- kernel 2: thresholded adjacency row-sum over one j-segment ----
__global__ __launch_bounds__(256) void k_adj(const float* __restrict__ xn,
                                             const float* __restrict__ in,
                                             float* __restrict__ pns) {
    int r = blockIdx.x * 256 + threadIdx.x;
    int seg = blockIdx.y;
    const float4* xp = reinterpret_cast<const float4*>(xn + r * 8);
    float4 xa = xp[0], xb = xp[1];
    float x0=xa.x, x1=xa.y, x2=xa.z, x3=xa.w, x4=xb.x, x5=xb.y, x6=xb.z, x7=xb.w;
    float acc0=0,acc1=0,acc2=0,acc3=0,acc4=0,acc5=0,acc6=0,acc7=0;
    int j0 = seg * JCH;
    #pragma unroll 4
    for (int t = 0; t < JCH; ++t) {
        int j = j0 + t;
        const float4* jp = reinterpret_cast<const float4*>(xn + j * 8);
        float4 a = jp[0], b = jp[1];
        float d = x0*a.x + x1*a.y + x2*a.z + x3*a.w
                + x4*b.x + x5*b.y + x6*b.z + x7*b.w;
        float fid = d * d;
        if (fid >= 0.8f && j != r) {
            const float4* ip = reinterpret_cast<const float4*>(in + j * 8);
            float4 u = ip[0], v = ip[1];
            acc0 += u.x; acc1 += u.y; acc2 += u.z; acc3 += u.w;
            acc4 += v.x; acc5 += v.y; acc6 += v.z; acc7 += v.w;
        }
    }
    float4* o = reinterpret_cast<float4*>(pns + ((size_t)seg * NN + r) * 8);
    o[0] = make_float4(acc0, acc1, acc2, acc3);
    o[1] = make_float4(acc4, acc5, acc6, acc7);
}

// ---- kernel 3: reduce partials, GNN linear+relu, q/k projections ----
__global__ __launch_bounds__(256) void k_diff(const float* __restrict__ pns,
                                              const float* __restrict__ gw,
                                              const float* __restrict__ gb,
                                              const float* __restrict__ rot,
                                              const float* __restrict__ ent,
                                              float* __restrict__ dif,
                                              float* __restrict__ qsb,
                                              float* __restrict__ kkb) {
    int r = blockIdx.x * 256 + threadIdx.x;
    float ns[8] = {0,0,0,0,0,0,0,0};
    for (int s = 0; s < SSEG; ++s) {
        const float4* p = reinterpret_cast<const float4*>(pns + ((size_t)s * NN + r) * 8);
        float4 a = p[0], b = p[1];
        ns[0]+=a.x; ns[1]+=a.y; ns[2]+=a.z; ns[3]+=a.w;
        ns[4]+=b.x; ns[5]+=b.y; ns[6]+=b.z; ns[7]+=b.w;
    }
    float df[8];
    #pragma unroll
    for (int d = 0; d < 8; ++d) {
        float v = gb[d];
        #pragma unroll
        for (int e = 0; e < 8; ++e) v += ns[e] * gw[d * 8 + e];
        df[d] = fmaxf(v, 0.0f);
    }
    const float QSC = (float)(1.4426950408889634 / 2.8284271247461903); // log2(e)/sqrt(8)
    #pragma unroll
    for (int d = 0; d < 8; ++d) {
        float vq = 0.0f, vk = 0.0f;
        #pragma unroll
        for (int e = 0; e < 8; ++e) {
            vq += df[e] * rot[e * 8 + d];
            vk += df[e] * ent[e * 8 + d];
        }
        qsb[r * 8 + d] = vq * QSC;
        kkb[r * 8 + d] = vk;
    }
    float4* o = reinterpret_cast<float4*>(dif + r * 8);
    o[0] = make_float4(df[0], df[1], df[2], df[3]);
    o[1] = make_float4(df[4], df[5], df[6], df[7]);
}

// ---- kernel 4: online-softmax attention partials over one j-segment ----
__global__ __launch_bounds__(256) void k_attn(const float* __restrict__ qsb,
                                              const float* __restrict__ kkb,
                                              const float* __restrict__ dif,
                                              float* __restrict__ pacc,
                                              float* __restrict__ pm,
                                              float* __restrict__ psum) {
    int r = blockIdx.x * 256 + threadIdx.x;
    int seg = blockIdx.y;
    const float4* qp = reinterpret_cast<const float4*>(qsb + r * 8);
    float4 qa = qp[0], qb = qp[1];
    float q0=qa.x, q1=qa.y, q2=qa.z, q3=qa.w, q4=qb.x, q5=qb.y, q6=qb.z, q7=qb.w;
    float m = -__builtin_huge_valf(), sum = 0.0f;
    float a0=0,a1=0,a2=0,a3=0,a4=0,a5=0,a6=0,a7=0;
    int j0 = seg * JCH;
    #pragma unroll 2
    for (int t = 0; t < JCH; ++t) {
        int j = j0 + t;
        const float4* kp = reinterpret_cast<const float4*>(kkb + j * 8);
        float4 ka = kp[0], kb = kp[1];
        const float4* dp = reinterpret_cast<const float4*>(dif + j * 8);
        float4 da = dp[0], db = dp[1];
        float s = q0*ka.x + q1*ka.y + q2*ka.z + q3*ka.w
                + q4*kb.x + q5*kb.y + q6*kb.z + q7*kb.w;
        if (s > m) {
            float c = exp2f(m - s);
            m = s;
            sum = sum * c + 1.0f;
            a0 = a0*c + da.x; a1 = a1*c + da.y; a2 = a2*c + da.z; a3 = a3*c + da.w;
            a4 = a4*c + db.x; a5 = a5*c + db.y; a6 = a6*c + db.z; a7 = a7*c + db.w;
        } else {
            float p = exp2f(s - m);
            sum += p;
            a0 += p*da.x; a1 += p*da.y; a2 += p*da.z; a3 += p*da.w;
            a4 += p*db.x; a5 += p*db.y; a6 += p*db.z; a7 += p*db.w;
        }
    }
    size_t base = (size_t)seg * NN + r;
    float4* o = reinterpret_cast<float4*>(pacc + base * 8);
    o[0] = make_float4(a0, a1, a2, a3);
    o[1] = make_float4(a4, a5, a6, a7);
    pm[base] = m;
    psum[base] = sum;
}

// ---- kernel 5: merge attention partials + QCNN stack ----
__global__ __launch_bounds__(256) void k_merge(const float* __restrict__ pacc,
                                               const float* __restrict__ pm,
                                               const float* __restrict__ psum,
                                               const float* __restrict__ qw0, const float* __restrict__ qb0,
                                               const float* __restrict__ qw1, const float* __restrict__ qb1,
                                               const float* __restrict__ qw2, const float* __restrict__ qb2,
                                               const float* __restrict__ qw3, const float* __restrict__ qb3,
                                               const float* __restrict__ qw4, const float* __restrict__ qb4,
                                               const float* __restrict__ qw5, const float* __restrict__ qb5,
                                               float* __restrict__ out) {
    int r = blockIdx.x * 256 + threadIdx.x;
    float M = -__builtin_huge_valf();
    for (int s = 0; s < SSEG; ++s) M = fmaxf(M, pm[(size_t)s * NN + r]);
    float T = 0.0f;
    float A[8] = {0,0,0,0,0,0,0,0};
    for (int s = 0; s < SSEG; ++s) {
        size_t base = (size_t)s * NN + r;
        float c = exp2f(pm[base] - M);
        T += psum[base] * c;
        const float4* p = reinterpret_cast<const float4*>(pacc + base * 8);
        float4 a = p[0], b = p[1];
        A[0]+=c*a.x; A[1]+=c*a.y; A[2]+=c*a.z; A[3]+=c*a.w;
        A[4]+=c*b.x; A[5]+=c*b.y; A[6]+=c*b.z; A[7]+=c*b.w;
    }
    float invT = 1.0f / T;
    float h0[8];
    #pragma unroll
    for (int d = 0; d < 8; ++d) h0[d] = A[d] * invT;

    float h1[16];
    #pragma unroll
    for (int t = 0; t < 16; ++t) {
        float v = qb0[t];
        #pragma unroll
        for (int e = 0; e < 8; ++e) v += h0[e] * qw0[t * 8 + e];
        h1[t] = tanhf(v);
    }
    float h2[16];
    #pragma unroll
    for (int t = 0; t < 16; ++t) {
        float v = qb1[t];
        #pragma unroll
        for (int e = 0; e < 16; ++e) v += h1[e] * qw1[t * 16 + e];
        h2[t] = tanhf(v);
    }
    float h3[12];
    #pragma unroll
    for (int t = 0; t < 12; ++t) {
        float v = qb2[t];
        #pragma unroll
        for (int e = 0; e < 16; ++e) v += h2[e] * qw2[t * 16 + e];
        h3[t] = tanhf(v);
    }
    float h4[8];
    #pragma unroll
    for (int t = 0; t < 8; ++t) {
        float v = qb3[t];
        #pragma unroll
        for (int e = 0; e < 12; ++e) v += h3[e] * qw3[t * 12 + e];
        h4[t] = tanhf(v);
    }
    float h5[4];
    #pragma unroll
    for (int t = 0; t < 4; ++t) {
        float v = qb4[t];
        #pragma unroll
        for (int e = 0; e < 8; ++e) v += h4[e] * qw4[t * 8 + e];
        h5[t] = tanhf(v);
    }
    float o = qb5[0];
    #pragma unroll
    for (int e = 0; e < 4; ++e) o += h5[e] * qw5[e];
    out[r] = 1.0f / (1.0f + expf(-o));
}

extern "C" void kernel_launch(void* const* d_in, const int* in_sizes, int n_in,
                              void* d_out, int out_size, void* d_ws, size_t ws_size,
                              hipStream_t stream) {
    const float* in  = (const float*)d_in[0];
    const float* rot = (const float*)d_in[1];
    const float* ent = (const float*)d_in[2];
    const float* gw  = (const float*)d_in[3];
    const float* gb  = (const float*)d_in[4];
    const float* qw0 = (const float*)d_in[5];
    const float* qb0 = (const float*)d_in[6];
    const float* qw1 = (const float*)d_in[7];
    const float* qb1 = (const float*)d_in[8];
    const float* qw2 = (const float*)d_in[9];
    const float* qb2 = (const float*)d_in[10];
    const float* qw3 = (const float*)d_in[11];
    const float* qb3 = (const float*)d_in[12];
    const float* qw4 = (const float*)d_in[13];
    const float* qb4 = (const float*)d_in[14];
    const float* qw5 = (const float*)d_in[15];
    const float* qb5 = (const float*)d_in[16];

    float* ws   = (float*)d_ws;
    float* xn   = ws + OFF_XN;
    float* pns  = ws + OFF_PNS;
    float* dif  = ws + OFF_DIF;
    float* qsb  = ws + OFF_QS;
    float* kkb  = ws + OFF_KK;
    float* pacc = ws + OFF_PACC;
    float* pm   = ws + OFF_PM;
    float* psum = ws + OFF_PSUM;

    dim3 blk(256);
    k_norm<<<dim3(NN / 256), blk, 0, stream>>>(in, xn);
    k_adj<<<dim3(NN / 256, SSEG), blk, 0, stream>>>(xn, in, pns);
    k_diff<<<dim3(NN / 256), blk, 0, stream>>>(pns, gw, gb, rot, ent, dif, qsb, kkb);
    k_attn<<<dim3(NN / 256, SSEG), blk, 0, stream>>>(qsb, kkb, dif, pacc, pm, psum);
    k_merge<<<dim3(NN / 256), blk, 0, stream>>>(pacc, pm, psum,
                                                qw0, qb0, qw1, qb1, qw2, qb2,
                                                qw3, qb3, qw4, qb4, qw5, qb5,
                                                (float*)out_size ? (float*)d_out : (float*)d_out);
}

// Round 2
// 127.633 us; speedup vs baseline: 1.2097x; 1.2097x over previous
//
#include <hip/hip_runtime.h>
#include <math.h>

#define NN 8192
#define SSEG 32
#define JCH (NN / SSEG)   // 256

// ---------------- workspace layout (in floats) ----------------
constexpr size_t OFF_XN   = 0;                                 // [NN][8] normalized rows
constexpr size_t OFF_PNS  = OFF_XN + (size_t)NN * 8;           // [SSEG][NN][8] partial neighbour sums
constexpr size_t OFF_DIF  = OFF_PNS + (size_t)SSEG * NN * 8;   // [NN][8] diffused
constexpr size_t OFF_QS   = OFF_DIF + (size_t)NN * 8;          // [NN][8] q pre-scaled by log2e/sqrt(8)
constexpr size_t OFF_KK   = OFF_QS + (size_t)NN * 8;           // [NN][8] k
constexpr size_t OFF_PACC = OFF_KK + (size_t)NN * 8;           // [SSEG][NN][8] partial attn accum
constexpr size_t OFF_PM   = OFF_PACC + (size_t)SSEG * NN * 8;  // [SSEG][NN] partial max
constexpr size_t OFF_PSUM = OFF_PM + (size_t)SSEG * NN;        // [SSEG][NN] partial sum

// ---------------- kernel 1: row normalize (unchanged, bit-exact vs round 1) ----------------
__global__ __launch_bounds__(256) void k_norm(const float* __restrict__ in,
                                              float* __restrict__ xn) {
    int r = blockIdx.x * 256 + threadIdx.x;
    const float4* p = reinterpret_cast<const float4*>(in + r * 8);
    float4 a = p[0], b = p[1];
    float ss = a.x*a.x + a.y*a.y + a.z*a.z + a.w*a.w
             + b.x*b.x + b.y*b.y + b.z*b.z + b.w*b.w;
    float inv = 1.0f / (sqrtf(ss) + 1e-12f);
    a.x *= inv; a.y *= inv; a.z *= inv; a.w *= inv;
    b.x *= inv; b.y *= inv; b.z *= inv; b.w *= inv;
    float4* o = reinterpret_cast<float4*>(xn + r * 8);
    o[0] = a; o[1] = b;
}

// ---- kernel 2: thresholded adjacency row-sum, LDS-staged segment ----
__global__ __launch_bounds__(256) void k_adj(const float* __restrict__ xn,
                                             const float* __restrict__ in,
                                             float* __restrict__ pns) {
    __shared__ float4 sx4[JCH * 2];
    __shared__ float4 si4[JCH * 2];
    int tid = threadIdx.x;
    int r = blockIdx.x * 256 + tid;
    int seg = blockIdx.y;
    int j0 = seg * JCH;
    // stage segment: normalized rows + raw rows
    {
        const float4* xp = reinterpret_cast<const float4*>(xn + (size_t)(j0 + tid) * 8);
        sx4[tid * 2] = xp[0]; sx4[tid * 2 + 1] = xp[1];
        const float4* ip = reinterpret_cast<const float4*>(in + (size_t)(j0 + tid) * 8);
        si4[tid * 2] = ip[0]; si4[tid * 2 + 1] = ip[1];
    }
    const float4* xp = reinterpret_cast<const float4*>(xn + (size_t)r * 8);
    float4 xa = xp[0], xb = xp[1];
    float x0=xa.x, x1=xa.y, x2=xa.z, x3=xa.w, x4=xb.x, x5=xb.y, x6=xb.z, x7=xb.w;
    __syncthreads();
    float acc0=0,acc1=0,acc2=0,acc3=0,acc4=0,acc5=0,acc6=0,acc7=0;
    #pragma unroll 8
    for (int t = 0; t < JCH; ++t) {
        float4 a = sx4[t * 2], b = sx4[t * 2 + 1];
        float d = x0*a.x + x1*a.y + x2*a.z + x3*a.w
                + x4*b.x + x5*b.y + x6*b.z + x7*b.w;
        float fid = d * d;
        if (fid >= 0.8f && (j0 + t) != r) {
            float4 u = si4[t * 2], v = si4[t * 2 + 1];
            acc0 += u.x; acc1 += u.y; acc2 += u.z; acc3 += u.w;
            acc4 += v.x; acc5 += v.y; acc6 += v.z; acc7 += v.w;
        }
    }
    float4* o = reinterpret_cast<float4*>(pns + ((size_t)seg * NN + r) * 8);
    o[0] = make_float4(acc0, acc1, acc2, acc3);
    o[1] = make_float4(acc4, acc5, acc6, acc7);
}

// ---- kernel 3: reduce partials, GNN linear+relu, q/k projections (unchanged) ----
__global__ __launch_bounds__(256) void k_diff(const float* __restrict__ pns,
                                              const float* __restrict__ gw,
                                              const float* __restrict__ gb,
                                              const float* __restrict__ rot,
                                              const float* __restrict__ ent,
                                              float* __restrict__ dif,
                                              float* __restrict__ qsb,
                                              float* __restrict__ kkb) {
    int r = blockIdx.x * 256 + threadIdx.x;
    float ns[8] = {0,0,0,0,0,0,0,0};
    for (int s = 0; s < SSEG; ++s) {
        const float4* p = reinterpret_cast<const float4*>(pns + ((size_t)s * NN + r) * 8);
        float4 a = p[0], b = p[1];
        ns[0]+=a.x; ns[1]+=a.y; ns[2]+=a.z; ns[3]+=a.w;
        ns[4]+=b.x; ns[5]+=b.y; ns[6]+=b.z; ns[7]+=b.w;
    }
    float df[8];
    #pragma unroll
    for (int d = 0; d < 8; ++d) {
        float v = gb[d];
        #pragma unroll
        for (int e = 0; e < 8; ++e) v += ns[e] * gw[d * 8 + e];
        df[d] = fmaxf(v, 0.0f);
    }
    const float QSC = (float)(1.4426950408889634 / 2.8284271247461903); // log2(e)/sqrt(8)
    #pragma unroll
    for (int d = 0; d < 8; ++d) {
        float vq = 0.0f, vk = 0.0f;
        #pragma unroll
        for (int e = 0; e < 8; ++e) {
            vq += df[e] * rot[e * 8 + d];
            vk += df[e] * ent[e * 8 + d];
        }
        qsb[r * 8 + d] = vq * QSC;
        kkb[r * 8 + d] = vk;
    }
    float4* o = reinterpret_cast<float4*>(dif + r * 8);
    o[0] = make_float4(df[0], df[1], df[2], df[3]);
    o[1] = make_float4(df[4], df[5], df[6], df[7]);
}

// ---- kernel 4: chunked-flash attention partials over one j-segment ----
__global__ __launch_bounds__(256) void k_attn(const float* __restrict__ qsb,
                                              const float* __restrict__ kkb,
                                              const float* __restrict__ dif,
                                              float* __restrict__ pacc,
                                              float* __restrict__ pm,
                                              float* __restrict__ psum) {
    __shared__ float4 sk4[JCH * 2];
    __shared__ float4 sd4[JCH * 2];
    int tid = threadIdx.x;
    int r = blockIdx.x * 256 + tid;
    int seg = blockIdx.y;
    int j0 = seg * JCH;
    {
        const float4* kp = reinterpret_cast<const float4*>(kkb + (size_t)(j0 + tid) * 8);
        sk4[tid * 2] = kp[0]; sk4[tid * 2 + 1] = kp[1];
        const float4* dp = reinterpret_cast<const float4*>(dif + (size_t)(j0 + tid) * 8);
        sd4[tid * 2] = dp[0]; sd4[tid * 2 + 1] = dp[1];
    }
    const float4* qp = reinterpret_cast<const float4*>(qsb + (size_t)r * 8);
    float4 qa = qp[0], qb = qp[1];
    float q0=qa.x, q1=qa.y, q2=qa.z, q3=qa.w, q4=qb.x, q5=qb.y, q6=qb.z, q7=qb.w;
    __syncthreads();

    float m = -__builtin_huge_valf();
    float sum = 0.0f;
    float acc[8] = {0,0,0,0,0,0,0,0};

    for (int c = 0; c < JCH; c += 32) {
        // --- 32 independent score dots ---
        float s[32];
        #pragma unroll
        for (int u = 0; u < 32; ++u) {
            float4 ka = sk4[(c + u) * 2], kb = sk4[(c + u) * 2 + 1];
            s[u] = q0*ka.x + q1*ka.y + q2*ka.z + q3*ka.w
                 + q4*kb.x + q5*kb.y + q6*kb.z + q7*kb.w;
        }
        // --- tree max over the chunk ---
        float red[16];
        #pragma unroll
        for (int u = 0; u < 16; ++u) red[u] = fmaxf(s[2*u], s[2*u+1]);
        #pragma unroll
        for (int u = 0; u < 8; ++u) red[u] = fmaxf(red[2*u], red[2*u+1]);
        #pragma unroll
        for (int u = 0; u < 4; ++u) red[u] = fmaxf(red[2*u], red[2*u+1]);
        red[0] = fmaxf(red[0], red[1]);
        red[1] = fmaxf(red[2], red[3]);
        float cmax = fmaxf(red[0], red[1]);
        // --- single branchless rescale per chunk ---
        float mn = fmaxf(m, cmax);
        float resc = exp2f(m - mn);   // first chunk: exp2(-inf) = 0
        m = mn;
        sum *= resc;
        #pragma unroll
        for (int e = 0; e < 8; ++e) acc[e] *= resc;
        // --- 32 independent exps + 8-way-ILP accumulate ---
        float ps[4] = {0,0,0,0};
        #pragma unroll
        for (int u = 0; u < 32; ++u) {
            float p = exp2f(s[u] - m);
            ps[u & 3] += p;
            float4 da = sd4[(c + u) * 2], db = sd4[(c + u) * 2 + 1];
            acc[0] += p*da.x; acc[1] += p*da.y; acc[2] += p*da.z; acc[3] += p*da.w;
            acc[4] += p*db.x; acc[5] += p*db.y; acc[6] += p*db.z; acc[7] += p*db.w;
        }
        sum += (ps[0] + ps[1]) + (ps[2] + ps[3]);
    }

    size_t base = (size_t)seg * NN + r;
    float4* o = reinterpret_cast<float4*>(pacc + base * 8);
    o[0] = make_float4(acc[0], acc[1], acc[2], acc[3]);
    o[1] = make_float4(acc[4], acc[5], acc[6], acc[7]);
    pm[base] = m;
    psum[base] = sum;
}

// ---- kernel 5: merge attention partials + QCNN stack (unchanged) ----
__global__ __launch_bounds__(256) void k_merge(const float* __restrict__ pacc,
                                               const float* __restrict__ pm,
                                               const float* __restrict__ psum,
                                               const float* __restrict__ qw0, const float* __restrict__ qb0,
                                               const float* __restrict__ qw1, const float* __restrict__ qb1,
                                               const float* __restrict__ qw2, const float* __restrict__ qb2,
                                               const float* __restrict__ qw3, const float* __restrict__ qb3,
                                               const float* __restrict__ qw4, const float* __restrict__ qb4,
                                               const float* __restrict__ qw5, const float* __restrict__ qb5,
                                               float* __restrict__ out) {
    int r = blockIdx.x * 256 + threadIdx.x;
    float M = -__builtin_huge_valf();
    for (int s = 0; s < SSEG; ++s) M = fmaxf(M, pm[(size_t)s * NN + r]);
    float T = 0.0f;
    float A[8] = {0,0,0,0,0,0,0,0};
    for (int s = 0; s < SSEG; ++s) {
        size_t base = (size_t)s * NN + r;
        float c = exp2f(pm[base] - M);
        T += psum[base] * c;
        const float4* p = reinterpret_cast<const float4*>(pacc + base * 8);
        float4 a = p[0], b = p[1];
        A[0]+=c*a.x; A[1]+=c*a.y; A[2]+=c*a.z; A[3]+=c*a.w;
        A[4]+=c*b.x; A[5]+=c*b.y; A[6]+=c*b.z; A[7]+=c*b.w;
    }
    float invT = 1.0f / T;
    float h0[8];
    #pragma unroll
    for (int d = 0; d < 8; ++d) h0[d] = A[d] * invT;

    float h1[16];
    #pragma unroll
    for (int t = 0; t < 16; ++t) {
        float v = qb0[t];
        #pragma unroll
        for (int e = 0; e < 8; ++e) v += h0[e] * qw0[t * 8 + e];
        h1[t] = tanhf(v);
    }
    float h2[16];
    #pragma unroll
    for (int t = 0; t < 16; ++t) {
        float v = qb1[t];
        #pragma unroll
        for (int e = 0; e < 16; ++e) v += h1[e] * qw1[t * 16 + e];
        h2[t] = tanhf(v);
    }
    float h3[12];
    #pragma unroll
    for (int t = 0; t < 12; ++t) {
        float v = qb2[t];
        #pragma unroll
        for (int e = 0; e < 16; ++e) v += h2[e] * qw2[t * 16 + e];
        h3[t] = tanhf(v);
    }
    float h4[8];
    #pragma unroll
    for (int t = 0; t < 8; ++t) {
        float v = qb3[t];
        #pragma unroll
        for (int e = 0; e < 12; ++e) v += h3[e] * qw3[t * 12 + e];
        h4[t] = tanhf(v);
    }
    float h5[4];
    #pragma unroll
    for (int t = 0; t < 4; ++t) {
        float v = qb4[t];
        #pragma unroll
        for (int e = 0; e < 8; ++e) v += h4[e] * qw4[t * 8 + e];
        h5[t] = tanhf(v);
    }
    float o = qb5[0];
    #pragma unroll
    for (int e = 0; e < 4; ++e) o += h5[e] * qw5[e];
    out[r] = 1.0f / (1.0f + expf(-o));
}

extern "C" void kernel_launch(void* const* d_in, const int* in_sizes, int n_in,
                              void* d_out, int out_size, void* d_ws, size_t ws_size,
                              hipStream_t stream) {
    const float* in  = (const float*)d_in[0];
    const float* rot = (const float*)d_in[1];
    const float* ent = (const float*)d_in[2];
    const float* gw  = (const float*)d_in[3];
    const float* gb  = (const float*)d_in[4];
    const float* qw0 = (const float*)d_in[5];
    const float* qb0 = (const float*)d_in[6];
    const float* qw1 = (const float*)d_in[7];
    const float* qb1 = (const float*)d_in[8];
    const float* qw2 = (const float*)d_in[9];
    const float* qb2 = (const float*)d_in[10];
    const float* qw3 = (const float*)d_in[11];
    const float* qb3 = (const float*)d_in[12];
    const float* qw4 = (const float*)d_in[13];
    const float* qb4 = (const float*)d_in[14];
    const float* qw5 = (const float*)d_in[15];
    const float* qb5 = (const float*)d_in[16];

    float* ws   = (float*)d_ws;
    float* xn   = ws + OFF_XN;
    float* pns  = ws + OFF_PNS;
    float* dif  = ws + OFF_DIF;
    float* qsb  = ws + OFF_QS;
    float* kkb  = ws + OFF_KK;
    float* pacc = ws + OFF_PACC;
    float* pm   = ws + OFF_PM;
    float* psum = ws + OFF_PSUM;

    dim3 blk(256);
    k_norm<<<dim3(NN / 256), blk, 0, stream>>>(in, xn);
    k_adj<<<dim3(NN / 256, SSEG), blk, 0, stream>>>(xn, in, pns);
    k_diff<<<dim3(NN / 256), blk, 0, stream>>>(pns, gw, gb, rot, ent, dif, qsb, kkb);
    k_attn<<<dim3(NN / 256, SSEG), blk, 0, stream>>>(qsb, kkb, dif, pacc, pm, psum);
    k_merge<<<dim3(NN / 256), blk, 0, stream>>>(pacc, pm, psum,
                                                qw0, qb0, qw1, qb1, qw2, qb2,
                                                qw3, qb3, qw4, qb4, qw5, qb5,
                                                (float*)d_out);
}